// Round 5
// baseline (323.658 us; speedup 1.0000x reference)
//
#include <hip/hip_runtime.h>

#define BLOCK 512
#define TE 64   // edges per tile
#define TN 64   // nodes per tile
#define NTB 512 // edge grid blocks (2 per CU)

typedef float f32x4 __attribute__((ext_vector_type(4)));
typedef short s16x8 __attribute__((ext_vector_type(8)));

static __device__ __forceinline__ unsigned short f2bf(float f) {
    unsigned int u = __float_as_uint(f);
    u += 0x7FFFu + ((u >> 16) & 1u);          // round-to-nearest-even
    return (unsigned short)(u >> 16);
}
static __device__ __forceinline__ float bf2f(unsigned short s) {
    return __uint_as_float(((unsigned int)s) << 16);
}

// LDS-only barrier: waits LDS ops, does NOT drain vmcnt -> atomics/loads
// issued before it keep flying (T3/T4 counted-vmcnt pattern).
static __device__ __forceinline__ void bar_lds() {
    asm volatile("s_waitcnt lgkmcnt(0)" ::: "memory");
    __builtin_amdgcn_s_barrier();
    asm volatile("" ::: "memory");
}

// ---------------------------------------------------------------------------
// Edge kernel, software-pipelined with counted-vmcnt barriers.
// Per iteration (VMEM issue order matters for the vmcnt FIFO):
//  A: gather x(t)->regs [oldest] | prefetch ea/idx(t+1)->regs |
//     atomics(t-1) [newest, ride across barriers] | h(t)
//  BAR1 (lgkm only)
//  B: MFMA(t) | LDS-stage(t+1) (waits vmcnt(12): prefetch done, atomics fly) |
//     wvx=(acc+bias)*xg -> carry regs
//  BAR2 (lgkm only)
// ---------------------------------------------------------------------------
__global__ __launch_bounds__(BLOCK, 4) void edge_kernel(
    const float* __restrict__ x,     // [N][96]
    const int*   __restrict__ ei,    // [2][E]
    const float* __restrict__ ea,    // [E][17]
    const float* __restrict__ W1,    // [96][17]
    const float* __restrict__ b1,    // [96]
    const float* __restrict__ W2,    // [96][96]
    const float* __restrict__ b2,    // [96]
    float* __restrict__ agg,         // [N][96]
    int N, int E)
{
    __shared__ unsigned short sBh[9216];      // W2 hi, fragment-linear
    __shared__ unsigned short sBl[9216];      // W2 lo
    __shared__ unsigned short sAh[3][TE][40]; // h hi, chunk-major
    __shared__ unsigned short sAl[3][TE][40]; // h lo
    __shared__ float sW1[96][20];
    __shared__ float sea[TE][20];
    __shared__ float sb1[96];
    __shared__ int   ssrc[TE], sdst[TE];

    const int tid  = threadIdx.x;
    const int c    = tid & 31;
    const int g    = tid >> 5;
    const int lane = tid & 63;
    const int wv   = tid >> 6;
    const int mr   = wv & 3;
    const int ng   = wv >> 2;
    const int l15  = lane & 15;
    const int l4   = lane >> 4;

    const int ntiles = (E + TE - 1) / TE;

    // ---- prefetch tile0 into regs (flies under weight staging) ----
    const int pe = tid >> 3, ps = tid & 7;
    float pf0 = 0.f, pf1 = 0.f, pf2 = 0.f; int pidx = 0;
    int tile = blockIdx.x;
    {
        int e0n = tile * TE;
        int ee  = e0n + pe; if (ee >= E) ee = E - 1;
        const float* er = ea + (size_t)ee * 17;
        pf0 = er[ps];
        pf1 = er[ps + 8];
        if (ps == 0) pf2 = er[16];
        if (tid < TE)            { int e = e0n + tid;      pidx = (e < E) ? ei[e]     : 0; }
        else if (tid < 2 * TE)   { int e = e0n + tid - TE; pidx = (e < E) ? ei[E + e] : 0; }
    }

    // ---- one-time staging ----
    for (int idx = tid; idx < 96 * 20; idx += BLOCK) {
        int d = idx / 20, k = idx - d * 20;
        sW1[d][k] = (k < 17) ? W1[d * 17 + k] : 0.f;
    }
    for (int idx = tid; idx < 96 * 96; idx += BLOCK) {
        int d = idx / 96, k = idx - d * 96;
        float v = W2[idx];
        unsigned short hb = f2bf(v);
        int ngf = d / 48, tt = (d % 48) / 16, r = d & 15;
        int ch = k >> 5, kl4 = (k & 31) >> 3, sb = k & 7;
        int fo = ((((ngf * 3 + tt) * 3 + ch) * 4 + kl4) * 16 + r) * 8 + sb;
        sBh[fo] = hb;
        sBl[fo] = f2bf(v - bf2f(hb));
    }
    if (tid < 96) sb1[tid] = b1[tid];
    if (tid < TE) { sea[tid][17] = 0.f; sea[tid][18] = 0.f; sea[tid][19] = 0.f; }

    float bias[3]; int dv[3];
    #pragma unroll
    for (int t = 0; t < 3; ++t) {
        dv[t]   = (ng * 3 + t) * 16 + l15;
        bias[t] = b2[dv[t]];
    }

    __syncthreads();   // one-time: weights staged, tile0 prefetch drained

    // write tile0 stage
    sea[pe][ps]     = pf0;
    sea[pe][ps + 8] = pf1;
    if (ps == 0) sea[pe][16] = pf2;
    if (tid < TE)          ssrc[tid]      = pidx;
    else if (tid < 2 * TE) sdst[tid - TE] = pidx;
    __syncthreads();

    float p_wvx[12]; int p_dn[4]; int p_e0 = 0;
    const int first = blockIdx.x;

    for (; tile < ntiles; tile += NTB) {
        const int nxt = tile + NTB;

        // ===== Phase A =====
        // (1) gather x[src] for tile t -> regs  [oldest VMEM]
        int sg[4], ndn[4];
        #pragma unroll
        for (int j = 0; j < 4; ++j) {
            int elj = mr * 16 + l4 * 4 + j;
            sg[j]  = ssrc[elj];
            ndn[j] = sdst[elj];
        }
        float xg[12];
        #pragma unroll
        for (int t = 0; t < 3; ++t)
            #pragma unroll
            for (int j = 0; j < 4; ++j)
                xg[t * 4 + j] = x[(size_t)sg[j] * 96 + dv[t]];

        // (2) prefetch tile t+1 ea/idx -> regs
        if (nxt < ntiles) {
            int e0n = nxt * TE;
            int ee  = e0n + pe; if (ee >= E) ee = E - 1;
            const float* er = ea + (size_t)ee * 17;
            pf0 = er[ps];
            pf1 = er[ps + 8];
            if (ps == 0) pf2 = er[16];
            if (tid < TE)            { int e = e0n + tid;      pidx = (e < E) ? ei[e]     : 0; }
            else if (tid < 2 * TE)   { int e = e0n + tid - TE; pidx = (e < E) ? ei[E + e] : 0; }
        }

        // (3) previous tile's atomics [newest VMEM -> ride across barriers]
        if (tile != first) {
            #pragma unroll
            for (int t = 0; t < 3; ++t)
                #pragma unroll
                for (int j = 0; j < 4; ++j) {
                    int e = p_e0 + mr * 16 + l4 * 4 + j;
                    if (e < E)
                        atomicAdd(&agg[(size_t)p_dn[j] * 96 + dv[t]], p_wvx[t * 4 + j]);
                }
        }

        // (4) h = relu(ea @ W1^T + b1) -> bf16 hi/lo into sA
        {
            float hacc[4][3];
            #pragma unroll
            for (int i = 0; i < 4; ++i) {
                hacc[i][0] = sb1[c]; hacc[i][1] = sb1[c + 32]; hacc[i][2] = sb1[c + 64];
            }
            #pragma unroll
            for (int k0 = 0; k0 < 20; k0 += 4) {
                float4 w0 = *(const float4*)&sW1[c][k0];
                float4 w1 = *(const float4*)&sW1[c + 32][k0];
                float4 w2 = *(const float4*)&sW1[c + 64][k0];
                #pragma unroll
                for (int i = 0; i < 4; ++i) {
                    float4 av = *(const float4*)&sea[g * 4 + i][k0];
                    hacc[i][0] = fmaf(av.w, w0.w, fmaf(av.z, w0.z, fmaf(av.y, w0.y, fmaf(av.x, w0.x, hacc[i][0]))));
                    hacc[i][1] = fmaf(av.w, w1.w, fmaf(av.z, w1.z, fmaf(av.y, w1.y, fmaf(av.x, w1.x, hacc[i][1]))));
                    hacc[i][2] = fmaf(av.w, w2.w, fmaf(av.z, w2.z, fmaf(av.y, w2.y, fmaf(av.x, w2.x, hacc[i][2]))));
                }
            }
            #pragma unroll
            for (int i = 0; i < 4; ++i) {
                int e = g * 4 + i;
                #pragma unroll
                for (int j = 0; j < 3; ++j) {
                    float v = fmaxf(hacc[i][j], 0.f);
                    unsigned short hb = f2bf(v);
                    sAh[j][e][c] = hb;
                    sAl[j][e][c] = f2bf(v - bf2f(hb));
                }
            }
        }
        bar_lds();   // BAR1: sA visible; vmcnt NOT drained

        // ===== Phase B =====
        // MFMA split-3
        f32x4 acc[3];
        #pragma unroll
        for (int t = 0; t < 3; ++t) acc[t] = (f32x4){0.f, 0.f, 0.f, 0.f};
        const int arow = mr * 16 + l15;
        #pragma unroll
        for (int chunk = 0; chunk < 3; ++chunk) {
            s16x8 a_hi = *(const s16x8*)&sAh[chunk][arow][l4 * 8];
            s16x8 a_lo = *(const s16x8*)&sAl[chunk][arow][l4 * 8];
            #pragma unroll
            for (int t = 0; t < 3; ++t) {
                const int base = (((ng * 3 + t) * 3 + chunk) * 64 + lane) * 8;
                s16x8 b_hi = *(const s16x8*)&sBh[base];
                s16x8 b_lo = *(const s16x8*)&sBl[base];
                acc[t] = __builtin_amdgcn_mfma_f32_16x16x32_bf16(a_hi, b_hi, acc[t], 0, 0, 0);
                acc[t] = __builtin_amdgcn_mfma_f32_16x16x32_bf16(a_hi, b_lo, acc[t], 0, 0, 0);
                acc[t] = __builtin_amdgcn_mfma_f32_16x16x32_bf16(a_lo, b_hi, acc[t], 0, 0, 0);
            }
        }

        // stage tile t+1 (compiler waits counted vmcnt for pf regs; atomics ride)
        if (nxt < ntiles) {
            sea[pe][ps]     = pf0;
            sea[pe][ps + 8] = pf1;
            if (ps == 0) sea[pe][16] = pf2;
            if (tid < TE)          ssrc[tid]      = pidx;
            else if (tid < 2 * TE) sdst[tid - TE] = pidx;
        }

        // epilogue values -> carry regs
        #pragma unroll
        for (int t = 0; t < 3; ++t)
            #pragma unroll
            for (int j = 0; j < 4; ++j)
                p_wvx[t * 4 + j] = (acc[t][j] + bias[t]) * xg[t * 4 + j];
        #pragma unroll
        for (int j = 0; j < 4; ++j) p_dn[j] = ndn[j];
        p_e0 = tile * TE;

        bar_lds();   // BAR2: tile t+1 stage visible; vmcnt NOT drained
    }

    // tail: last tile's atomics (dispatch-end fence guarantees completion)
    if (first < ntiles) {
        #pragma unroll
        for (int t = 0; t < 3; ++t)
            #pragma unroll
            for (int j = 0; j < 4; ++j) {
                int e = p_e0 + mr * 16 + l4 * 4 + j;
                if (e < E)
                    atomicAdd(&agg[(size_t)p_dn[j] * 96 + dv[t]], p_wvx[t * 4 + j]);
            }
    }
}

// ---------------------------------------------------------------------------
// Kernel 2: out = relu(x @ Ws^T + bs + agg @ Wn^T + bn)  (unchanged)
// ---------------------------------------------------------------------------
__global__ __launch_bounds__(BLOCK, 4) void node_kernel(
    const float* __restrict__ x,
    const float* __restrict__ agg,
    const float* __restrict__ Ws, const float* __restrict__ bs,
    const float* __restrict__ Wn, const float* __restrict__ bn,
    float* __restrict__ out, int N)
{
    __shared__ float sW[96][100];
    __shared__ float sxa[TN][100];
    __shared__ float sbias[96];

    const int tid = threadIdx.x;
    const int c = tid & 31, g = tid >> 5;
    const int n0 = blockIdx.x * TN;

    if (tid < 96) sbias[tid] = bs[tid] + bn[tid];

    float acc[4][3];
    #pragma unroll
    for (int i = 0; i < 4; ++i)
        for (int j = 0; j < 3; ++j) acc[i][j] = 0.f;

    for (int ph = 0; ph < 2; ++ph) {
        const float* __restrict__ W   = ph ? Wn : Ws;
        const float* __restrict__ src = ph ? agg : x;
        __syncthreads();
        for (int idx = tid; idx < 96 * 24; idx += BLOCK) {
            int d = idx / 24, kq = idx - d * 24;
            *(float4*)&sW[d][kq * 4] = *(const float4*)&W[d * 96 + kq * 4];
        }
        for (int idx = tid; idx < TN * 24; idx += BLOCK) {
            int n = idx / 24, kq = idx - n * 24;
            float4 v = make_float4(0.f, 0.f, 0.f, 0.f);
            if (n0 + n < N) v = *(const float4*)&src[(size_t)(n0 + n) * 96 + kq * 4];
            *(float4*)&sxa[n][kq * 4] = v;
        }
        __syncthreads();
        #pragma unroll 2
        for (int k0 = 0; k0 < 96; k0 += 4) {
            float4 w0 = *(const float4*)&sW[c][k0];
            float4 w1 = *(const float4*)&sW[c + 32][k0];
            float4 w2 = *(const float4*)&sW[c + 64][k0];
            #pragma unroll
            for (int i = 0; i < 4; ++i) {
                float4 xv = *(const float4*)&sxa[g * 4 + i][k0];
                acc[i][0] = fmaf(xv.w, w0.w, fmaf(xv.z, w0.z, fmaf(xv.y, w0.y, fmaf(xv.x, w0.x, acc[i][0]))));
                acc[i][1] = fmaf(xv.w, w1.w, fmaf(xv.z, w1.z, fmaf(xv.y, w1.y, fmaf(xv.x, w1.x, acc[i][1]))));
                acc[i][2] = fmaf(xv.w, w2.w, fmaf(xv.z, w2.z, fmaf(xv.y, w2.y, fmaf(xv.x, w2.x, acc[i][2]))));
            }
        }
    }

    #pragma unroll
    for (int i = 0; i < 4; ++i) {
        int n = n0 + g * 4 + i;
        if (n < N) {
            out[(size_t)n * 96 + c]      = fmaxf(acc[i][0] + sbias[c], 0.f);
            out[(size_t)n * 96 + c + 32] = fmaxf(acc[i][1] + sbias[c + 32], 0.f);
            out[(size_t)n * 96 + c + 64] = fmaxf(acc[i][2] + sbias[c + 64], 0.f);
        }
    }
}

extern "C" void kernel_launch(void* const* d_in, const int* in_sizes, int n_in,
                              void* d_out, int out_size, void* d_ws, size_t ws_size,
                              hipStream_t stream) {
    const float* x  = (const float*)d_in[0];
    const int*   ei = (const int*)d_in[1];
    const float* ea = (const float*)d_in[2];
    const float* W1 = (const float*)d_in[3];
    const float* b1 = (const float*)d_in[4];
    const float* W2 = (const float*)d_in[5];
    const float* b2 = (const float*)d_in[6];
    const float* Ws = (const float*)d_in[7];
    const float* bs = (const float*)d_in[8];
    const float* Wn = (const float*)d_in[9];
    const float* bn = (const float*)d_in[10];
    float* out = (float*)d_out;

    const int N = in_sizes[0] / 96;
    const int E = in_sizes[2] / 17;

    float* agg = (ws_size >= (size_t)N * 96 * sizeof(float)) ? (float*)d_ws : out;
    hipMemsetAsync(agg, 0, (size_t)N * 96 * sizeof(float), stream);

    edge_kernel<<<NTB, BLOCK, 0, stream>>>(x, ei, ea, W1, b1, W2, b2, agg, N, E);
    node_kernel<<<(N + TN - 1) / TN, BLOCK, 0, stream>>>(x, agg, Ws, bs, Wn, bn, out, N);
}